// Round 1
// baseline (163.106 us; speedup 1.0000x reference)
//
#include <hip/hip_runtime.h>

// YOLO-style loss: y_pred (1024,28,28,30) f32, y_true (1024,28,28,5) f32 -> scalar f32.
// Memory-bound reduction: ~112.6 MB read, ~18us roofline at 6.3 TB/s.

#define S_GRID 28
#define N_CELLS (1024 * S_GRID * S_GRID)

__device__ __forceinline__ float iou_calc(float bx, float by, float bw, float bh,
                                          float tx, float ty, float tw, float th,
                                          float gi, float gj) {
    // corners for pred box (a)
    float acx = (gj + bx) * 8.0f;
    float acy = (gi + by) * 8.0f;
    float aw  = bw * 224.0f;
    float ah  = bh * 224.0f;
    float ax1 = acx - aw * 0.5f, ax2 = acx + aw * 0.5f;
    float ay1 = acy - ah * 0.5f, ay2 = acy + ah * 0.5f;
    // corners for true box (b)
    float bcx = (gj + tx) * 8.0f;
    float bcy = (gi + ty) * 8.0f;
    float btw = tw * 224.0f;
    float bth = th * 224.0f;
    float bx1 = bcx - btw * 0.5f, bx2 = bcx + btw * 0.5f;
    float by1 = bcy - bth * 0.5f, by2 = bcy + bth * 0.5f;

    float iw = fmaxf(fminf(ax2, bx2) - fmaxf(ax1, bx1), 0.0f);
    float ih = fmaxf(fminf(ay2, by2) - fmaxf(ay1, by1), 0.0f);
    float inter = iw * ih;
    float area_a = fmaxf(ax2 - ax1, 0.0f) * fmaxf(ay2 - ay1, 0.0f);
    float area_b = fmaxf(bx2 - bx1, 0.0f) * fmaxf(by2 - by1, 0.0f);
    return inter / (area_a + area_b - inter + 1e-12f);
}

__global__ void zero_out_kernel(float* out) {
    out[0] = 0.0f;
}

__global__ __launch_bounds__(256) void yolo_loss_kernel(const float* __restrict__ y_pred,
                                                        const float* __restrict__ y_true,
                                                        float* __restrict__ out) {
    int c = blockIdx.x * blockDim.x + threadIdx.x;
    float val = 0.0f;
    if (c < N_CELLS) {
        int ij = c % (S_GRID * S_GRID);
        float gi = (float)(ij / S_GRID);   // row index
        float gj = (float)(ij % S_GRID);   // col index

        // y_pred cell: 30 floats, 120B stride => 8B aligned: use float2 x15
        const float2* p2 = (const float2*)(y_pred + (size_t)c * 30);
        float pr[30];
#pragma unroll
        for (int k = 0; k < 15; ++k) {
            float2 v = p2[k];
            pr[2 * k]     = v.x;
            pr[2 * k + 1] = v.y;
        }
        // y_true cell: 5 floats, 20B stride => 4B aligned scalar loads
        const float* t = y_true + (size_t)c * 5;
        float tc = t[0], tx = t[1], ty = t[2], tw = t[3], th = t[4];

        float iou0 = iou_calc(pr[0], pr[1], pr[2], pr[3], tx, ty, tw, th, gi, gj);
        float iou1 = iou_calc(pr[5], pr[6], pr[7], pr[8], tx, ty, tw, th, gi, gj);
        bool choose1 = !(iou0 > iou1);

        float conf_pred = choose1 ? pr[9] : pr[4];
        float conf_true = choose1 ? iou1 : iou0;
        float xp = choose1 ? pr[5] : pr[0];
        float yp = choose1 ? pr[6] : pr[1];

        float dcf = conf_pred - conf_true;
        float loss_conf_obj = dcf * dcf;

        float d0 = xp - tx, d1 = yp - ty;
        float loss_coord = 5.0f * (d0 * d0 + d1 * d1);

        int cls = (int)tc - 1;   // -1 => one-hot all zeros
        float lcls = 0.0f;
#pragma unroll
        for (int k = 0; k < 20; ++k) {
            float oh = (k == cls) ? 1.0f : 0.0f;
            float d = pr[10 + k] - oh;
            lcls += d * d;
        }

        float loss_noobj = 0.5f * (pr[4] * pr[4] + pr[9] * pr[9]);

        bool obj = (tc != 0.0f);
        val = obj ? (loss_conf_obj + loss_coord + lcls) : loss_noobj;
    }

    // wave-64 reduction
#pragma unroll
    for (int off = 32; off > 0; off >>= 1) {
        val += __shfl_down(val, off, 64);
    }
    __shared__ float wsum[4];
    int lane = threadIdx.x & 63;
    int wid  = threadIdx.x >> 6;
    if (lane == 0) wsum[wid] = val;
    __syncthreads();
    if (threadIdx.x == 0) {
        float s = wsum[0] + wsum[1] + wsum[2] + wsum[3];
        atomicAdd(out, s * (1.0f / 1024.0f));
    }
}

extern "C" void kernel_launch(void* const* d_in, const int* in_sizes, int n_in,
                              void* d_out, int out_size, void* d_ws, size_t ws_size,
                              hipStream_t stream) {
    const float* y_pred = (const float*)d_in[0];
    const float* y_true = (const float*)d_in[1];
    float* out = (float*)d_out;

    zero_out_kernel<<<1, 1, 0, stream>>>(out);
    int blocks = (N_CELLS + 255) / 256;  // 3136
    yolo_loss_kernel<<<blocks, 256, 0, stream>>>(y_pred, y_true, out);
}